// Round 7
// baseline (120.871 us; speedup 1.0000x reference)
//
#include <hip/hip_runtime.h>
#include <stdint.h>

// Sampler: temperature -> top-k -> top-p -> softmax -> multinomial (threefry)
// Round-7: ONE fused kernel, one block (16 waves) per row.
//  - stream row, warp-aggregated collect of x >= 8.0 into LDS (~1143 cands)
//  - wave0: exact raw kth via ballot binary search, certify >= 8.0+4ULP,
//    margin-compact, scale, exact scaled kth + ties, rank-sort ~55
//  - all serial FP chains via wave-uniform __shfl (bit-exact order preserved)
//  - parachutes: block-wide exact search if certify fails; LDS path if ns>64

#define BLOCK  1024
#define CAPN   2048
#define SLOTS  (CAPN / 64)   // 32 register key slots (wave0 search)
#define WCAP   256
#define TOPP   0.9f
#define TOPT_F 8.0f
#define OK8    0xC1000000u   // orderKey(8.0f)

// Order-preserving float -> uint map (ascending float == ascending uint)
__device__ __forceinline__ unsigned orderKey(float x) {
  unsigned u = __float_as_uint(x);
  return (u & 0x80000000u) ? ~u : (u | 0x80000000u);
}

// JAX threefry2x32 (20 rounds), exact.
__device__ __forceinline__ void threefry2x32(unsigned k0, unsigned k1,
                                             unsigned x0, unsigned x1,
                                             unsigned &o0, unsigned &o1) {
  unsigned k2 = k0 ^ k1 ^ 0x1BD11BDAu;
  x0 += k0; x1 += k1;
#define TFR(rr) { x0 += x1; x1 = (x1 << (rr)) | (x1 >> (32 - (rr))); x1 ^= x0; }
  TFR(13) TFR(15) TFR(26) TFR(6)
  x0 += k1; x1 += k2 + 1u;
  TFR(17) TFR(29) TFR(16) TFR(24)
  x0 += k2; x1 += k0 + 2u;
  TFR(13) TFR(15) TFR(26) TFR(6)
  x0 += k0; x1 += k1 + 3u;
  TFR(17) TFR(29) TFR(16) TFR(24)
  x0 += k1; x1 += k2 + 4u;
  TFR(13) TFR(15) TFR(26) TFR(6)
  x0 += k2; x1 += k0 + 5u;
#undef TFR
  o0 = x0; o1 = x1;
}

__global__ __launch_bounds__(BLOCK) void k_all(
    const float* __restrict__ logits, const int* __restrict__ topk_ptr,
    int* __restrict__ out, int V) {
  __shared__ float    bufv[CAPN];      // 8 KB raw candidates
  __shared__ int      bufi[CAPN];      // 8 KB
  __shared__ float    wv[WCAP];        // margin set (scaled)
  __shared__ int      wi[WCAP];
  __shared__ float    sv[WCAP];        // sorted (desc, idx asc)
  __shared__ int      si[WCAP];
  __shared__ float    evl[WCAP];       // ns>64 fallback only
  __shared__ short    ordl[WCAP];
  __shared__ unsigned lcnt, wcnt;
  __shared__ int      s_slow, s_tot;
  __shared__ unsigned s_thr;
  __shared__ int      redc[BLOCK / 64];

  const int tid = threadIdx.x, lane = tid & 63, wid = tid >> 6;
  const int row = blockIdx.x;
  const float* __restrict__ rp = logits + (size_t)row * (size_t)V;
  const float4* __restrict__ rp4 = (const float4*)rp;
  const int V4 = V >> 2;

  int k = topk_ptr[0];
  if (k < 1) k = 1;
  if (k > V) k = V;

  if (tid == 0) { lcnt = 0u; wcnt = 0u; }
  __syncthreads();

  // warp-aggregated push of qualifying elements into LDS buffer
#define PUSH(v_, idx_) do {                                             \
    bool q_ = (v_) >= TOPT_F;                                           \
    unsigned long long m_ = __ballot(q_);                               \
    if (q_) {                                                           \
      int ldr_ = __ffsll((unsigned long long)m_) - 1;                   \
      unsigned base_;                                                   \
      if (lane == ldr_) base_ = atomicAdd(&lcnt, (unsigned)__popcll(m_)); \
      base_ = __shfl(base_, ldr_);                                      \
      unsigned p_ = base_ + (unsigned)__popcll(m_ & ((1ull << lane) - 1ull)); \
      if (p_ < CAPN) { bufv[p_] = (v_); bufi[p_] = (idx_); }            \
    } } while (0)

  // main stream: 4-deep unrolled, bounds-free body
  const int V4m = V4 & ~(4 * BLOCK - 1);
  for (int base = 0; base < V4m; base += 4 * BLOCK) {
    const int i0 = base + tid;
    float4 a = rp4[i0];
    float4 b = rp4[i0 + BLOCK];
    float4 c = rp4[i0 + 2 * BLOCK];
    float4 d = rp4[i0 + 3 * BLOCK];
    PUSH(a.x, (i0 << 2));                PUSH(a.y, (i0 << 2) + 1);
    PUSH(a.z, (i0 << 2) + 2);            PUSH(a.w, (i0 << 2) + 3);
    PUSH(b.x, ((i0 + BLOCK) << 2));      PUSH(b.y, ((i0 + BLOCK) << 2) + 1);
    PUSH(b.z, ((i0 + BLOCK) << 2) + 2);  PUSH(b.w, ((i0 + BLOCK) << 2) + 3);
    PUSH(c.x, ((i0 + 2 * BLOCK) << 2));     PUSH(c.y, ((i0 + 2 * BLOCK) << 2) + 1);
    PUSH(c.z, ((i0 + 2 * BLOCK) << 2) + 2); PUSH(c.w, ((i0 + 2 * BLOCK) << 2) + 3);
    PUSH(d.x, ((i0 + 3 * BLOCK) << 2));     PUSH(d.y, ((i0 + 3 * BLOCK) << 2) + 1);
    PUSH(d.z, ((i0 + 3 * BLOCK) << 2) + 2); PUSH(d.w, ((i0 + 3 * BLOCK) << 2) + 3);
  }
  for (int i = V4m + tid; i < V4; i += BLOCK) {
    float4 a = rp4[i];
    PUSH(a.x, (i << 2));     PUSH(a.y, (i << 2) + 1);
    PUSH(a.z, (i << 2) + 2); PUSH(a.w, (i << 2) + 3);
  }
  for (int i = (V4 << 2) + tid; i < V; i += BLOCK) PUSH(rp[i], i);
#undef PUSH
  __syncthreads();

  // wave0: exact raw kth among buffered; certify margin stays >= 8.0
  if (wid == 0) {
    const int n = ((int)lcnt > CAPN) ? CAPN : (int)lcnt;
    unsigned key[SLOTS];
#pragma unroll
    for (int s = 0; s < SLOTS; ++s) {
      int i = lane + (s << 6);
      key[s] = (i < n) ? orderKey(bufv[i]) : 0u;
    }
    bool ok = (lcnt <= (unsigned)CAPN) && (n >= k);
    unsigned kraw = 0u;
    if (ok) {
      unsigned lo = 1u, hi = 0xFFFFFFFFu;
      while (lo < hi) {
        unsigned mid = lo + ((hi - lo + 1u) >> 1);
        int c = 0;
#pragma unroll
        for (int s = 0; s < SLOTS; ++s)
          if ((s << 6) < n) c += __popcll(__ballot(key[s] >= mid));
        if (c >= k) lo = mid; else hi = mid - 1u;
      }
      kraw = lo;
      ok = (kraw >= OK8 + 4u);  // 4-ULP margin inside the >=8.0 buffer
    }
    if (lane == 0) { s_slow = ok ? 0 : 1; s_thr = ok ? (kraw - 4u) : 0u; }
  }
  __syncthreads();

  if (s_slow) {
    // parachute: block-wide exact binary search over the full row (L2-warm)
    unsigned lo = 1u, hi = 0xFFFFFFFFu;
    while (lo < hi) {
      unsigned mid = lo + ((hi - lo + 1u) >> 1);
      int c = 0;
      for (int i = tid; i < V; i += BLOCK) c += (orderKey(rp[i]) >= mid);
      for (int o = 32; o; o >>= 1) c += __shfl_down(c, o);
      if (lane == 0) redc[wid] = c;
      __syncthreads();
      if (tid == 0) {
        int t = 0;
        for (int w = 0; w < BLOCK / 64; ++w) t += redc[w];
        s_tot = t;
      }
      __syncthreads();
      if (s_tot >= k) lo = mid; else hi = mid - 1u;
      __syncthreads();  // redc write-after-read fence for next iter
    }
    if (tid == 0) { lcnt = 0u; s_thr = (lo >= 5u) ? lo - 4u : 1u; }
    __syncthreads();
    const unsigned thr = s_thr;
    for (int i = tid; i < V; i += BLOCK) {
      float x = rp[i];
      if (orderKey(x) >= thr) {
        unsigned p = atomicAdd(&lcnt, 1u);
        if (p < CAPN) { bufv[p] = x; bufi[p] = i; }
      }
    }
    __syncthreads();
  }

  if (wid != 0) return;   // tail is single-wave; no more barriers

  // ---- wave0 tail ----
  const int n = ((int)lcnt > CAPN) ? CAPN : (int)lcnt;
  const unsigned thr = s_thr;

  // margin-compact + temperature scale (IEEE div, matches ref)
  for (int i = lane; i < n; i += 64) {
    float x = bufv[i];
    if (orderKey(x) >= thr) {
      unsigned p = atomicAdd(&wcnt, 1u);
      if (p < WCAP) { wv[p] = x / 0.8f; wi[p] = bufi[i]; }
    }
  }
  int m = (int)wcnt;
  if (m > WCAP) m = WCAP;
  if (m == 0) { if (lane == 0) out[row] = V; return; }

  // exact scaled kth among margin set (== row's scaled kth; margin ⊇ top-k)
  unsigned skey[WCAP / 64];
#pragma unroll
  for (int s = 0; s < WCAP / 64; ++s) {
    int i = lane + (s << 6);
    skey[s] = (i < m) ? orderKey(wv[i]) : 0u;
  }
  const int kk = (k < m) ? k : m;
  unsigned lo = 1u, hi = 0xFFFFFFFFu;
  while (lo < hi) {
    unsigned mid = lo + ((hi - lo + 1u) >> 1);
    int c = 0;
#pragma unroll
    for (int s = 0; s < WCAP / 64; ++s)
      c += __popcll(__ballot(skey[s] >= mid));
    if (c >= kk) lo = mid; else hi = mid - 1u;
  }
  const unsigned kvs = lo;
  int ns = 0;
#pragma unroll
  for (int s = 0; s < WCAP / 64; ++s)
    ns += __popcll(__ballot(skey[s] >= kvs));   // top-k + ties at kth value

  // rank-sort margin set: scaled desc, idx asc (== ref stable argsort);
  // survivors are then exactly the first ns sorted entries
  for (int i = lane; i < m; i += 64) {
    float v = wv[i];
    int   id = wi[i];
    int   rk = 0;
    for (int j = 0; j < m; ++j) {
      float vj = wv[j];
      rk += (vj > v) || (vj == v && wi[j] < id);
    }
    sv[rk] = v;
    si[rk] = id;
  }

  // r = uniform from fold_in(key(0), 1), partitionable threefry path
  unsigned tk0, tk1, o0, o1;
  threefry2x32(0u, 0u, 0u, 1u, tk0, tk1);
  threefry2x32(tk0, tk1, 0u, (unsigned)row, o0, o1);
  unsigned bits = o0 ^ o1;
  float r0 = __uint_as_float((bits >> 9) | 0x3F800000u) - 1.0f;
  const float rr = (r0 < 0.f) ? 0.f : r0;

  if (ns <= 64) {
    // shfl fast path: lane i holds sorted element i; serial chains wave-uniform
    float myv  = (lane < ns) ? sv[lane] : 0.f;
    int   myid = (lane < ns) ? si[lane] : 0x7FFFFFFF;
    const float mx = __shfl(myv, 0);
    float mye = (lane < ns) ? expf(myv - mx) : 0.f;

    float S = 0.f;
    for (int i = 0; i < ns; ++i) S += __shfl(mye, i);
    float c = 0.f;
    int K = ns;
    for (int i = 0; i < ns; ++i) {
      if (i > 0 && c > TOPP) { K = i; break; }   // remove[i] = cdf[i-1] > p
      c += __shfl(mye, i) / S;
    }
    float S2 = 0.f;
    for (int i = 0; i < K; ++i) S2 += __shfl(mye, i);

    int rk = 0;
    for (int j = 0; j < K; ++j) {
      int idj = __shfl(myid, j);
      rk += (idj < myid);
    }
    float c2 = 0.f;
    int ans = V;   // matches sum(cdf <= r) when r beyond total mass
    for (int t = 0; t < K; ++t) {
      unsigned long long mm = __ballot((lane < K) && (rk == t));
      int src = __ffsll((unsigned long long)mm) - 1;
      c2 += __shfl(mye, src) / S2;
      if (c2 > rr) { ans = __shfl(myid, src); break; }
    }
    if (lane == 0) out[row] = ans;
    return;
  }

  // ---- LDS fallback (ns > 64; effectively never taken) ----
  for (int i = lane; i < ns; i += 64) evl[i] = expf(sv[i] - sv[0]);
  // index-rank among kept computed after K known; serial part on lane 0
  if (lane == 0) {
    float S = 0.f;
    for (int i = 0; i < ns; ++i) S += evl[i];
    float c = 0.f;
    int K = ns;
    for (int i = 0; i < ns; ++i) {
      if (i > 0 && c > TOPP) { K = i; break; }
      c += evl[i] / S;
    }
    float S2 = 0.f;
    for (int i = 0; i < K; ++i) S2 += evl[i];
    // rank kept by original index (serial; fallback only)
    for (int i = 0; i < K; ++i) {
      int id = si[i], rk2 = 0;
      for (int j = 0; j < K; ++j) rk2 += (si[j] < id);
      ordl[rk2] = (short)i;
    }
    float c2 = 0.f;
    int ans = V;
    for (int t = 0; t < K; ++t) {
      int i = ordl[t];
      c2 += evl[i] / S2;
      if (c2 > rr) { ans = si[i]; break; }
    }
    out[row] = ans;
  }
}

extern "C" void kernel_launch(void* const* d_in, const int* in_sizes, int n_in,
                              void* d_out, int out_size, void* d_ws, size_t ws_size,
                              hipStream_t stream) {
  const float* logits = (const float*)d_in[0];
  const int*   topk   = (const int*)d_in[1];
  int*         out    = (int*)d_out;
  const int B = out_size;              // 256 rows
  const int V = in_sizes[0] / B;       // 50257
  (void)d_ws; (void)ws_size; (void)n_in;
  hipLaunchKernelGGL(k_all, dim3(B), dim3(BLOCK), 0, stream,
                     logits, topk, out, V);
}